// Round 2
// baseline (451.744 us; speedup 1.0000x reference)
//
#include <hip/hip_runtime.h>

#define B_ 4
#define T_ 448
#define U_ 448
#define SKS_ 96
#define BKS_ 32
#define H_ 96
#define V_ 128

typedef __attribute__((ext_vector_type(8))) short bf16x8;
typedef __attribute__((ext_vector_type(4))) float f32x4;
typedef __attribute__((ext_vector_type(4))) int i32x4;

__device__ __forceinline__ unsigned short f2bf(float f) {
    unsigned int u = __float_as_uint(f);
    u += 0x7fffu + ((u >> 16) & 1u);   // round-to-nearest-even
    return (unsigned short)(u >> 16);
}
__device__ __forceinline__ float bf2f(unsigned short h) {
    return __uint_as_float(((unsigned int)h) << 16);
}
// load 8 consecutive f32 (16B-aligned) -> bf16x8
__device__ __forceinline__ bf16x8 load_cvt8(const float* __restrict__ p) {
    f32x4 a = *(const f32x4*)p;
    f32x4 c = *(const f32x4*)(p + 4);
    bf16x8 r;
    r[0] = (short)f2bf(a.x); r[1] = (short)f2bf(a.y);
    r[2] = (short)f2bf(a.z); r[3] = (short)f2bf(a.w);
    r[4] = (short)f2bf(c.x); r[5] = (short)f2bf(c.y);
    r[6] = (short)f2bf(c.z); r[7] = (short)f2bf(c.w);
    return r;
}

// ---------------------------------------------------------------------------
// Prep kernel, 256 threads/block:
//   blocks [0,28)  : sh  = s @ W_sh^T + b_sh            (MFMA, 64 rows/block)
//   blocks [28,56) : rbh = relu(b @ W_bh^T + b_bh)      (MFMA, 64 rows/block)
//   blocks [56,62) : repack W_out f32[128][96] -> bf16 ws [k8][n][8]
// ---------------------------------------------------------------------------
__global__ __launch_bounds__(256) void prep_kernel(
    const float* __restrict__ s, const float* __restrict__ b,
    const float* __restrict__ W_sh, const float* __restrict__ b_sh,
    const float* __restrict__ W_bh, const float* __restrict__ b_bh,
    const float* __restrict__ W_out,
    unsigned short* __restrict__ sh_ws,
    unsigned short* __restrict__ rbh_ws,
    unsigned short* __restrict__ w_ws)
{
    const int blk  = blockIdx.x;
    const int tid  = threadIdx.x;
    const int wave = tid >> 6;
    const int lane = tid & 63;
    const int n    = lane & 15;   // col (A: row m; B: col n; C: col)
    const int q    = lane >> 4;   // k-quad (C: row quad)

    if (blk < 28) {
        // ---- sh projection: rows of s, K=96, N=96 ----
        const int row0 = blk * 64 + wave * 16;
        bf16x8 af[3];
        #pragma unroll
        for (int ks = 0; ks < 3; ks++)
            af[ks] = load_cvt8(s + (size_t)(row0 + n) * SKS_ + ks * 32 + q * 8);
        f32x4 acc[6];
        #pragma unroll
        for (int nt = 0; nt < 6; nt++) acc[nt] = (f32x4){0.f, 0.f, 0.f, 0.f};
        #pragma unroll
        for (int ks = 0; ks < 3; ks++) {
            #pragma unroll
            for (int nt = 0; nt < 6; nt++) {
                bf16x8 bf = load_cvt8(W_sh + (size_t)(nt * 16 + n) * SKS_ + ks * 32 + q * 8);
                acc[nt] = __builtin_amdgcn_mfma_f32_16x16x32_bf16(af[ks], bf, acc[nt], 0, 0, 0);
            }
        }
        #pragma unroll
        for (int nt = 0; nt < 6; nt++) {
            const float bias = b_sh[nt * 16 + n];
            #pragma unroll
            for (int r = 0; r < 4; r++) {
                sh_ws[(size_t)(row0 + q * 4 + r) * H_ + nt * 16 + n] =
                    f2bf(acc[nt][r] + bias);
            }
        }
    } else if (blk < 56) {
        // ---- bh projection + relu: rows of b, K=32, N=96 ----
        const int row0 = (blk - 28) * 64 + wave * 16;
        bf16x8 af = load_cvt8(b + (size_t)(row0 + n) * BKS_ + q * 8);
        f32x4 acc[6];
        #pragma unroll
        for (int nt = 0; nt < 6; nt++) acc[nt] = (f32x4){0.f, 0.f, 0.f, 0.f};
        #pragma unroll
        for (int nt = 0; nt < 6; nt++) {
            bf16x8 bf = load_cvt8(W_bh + (size_t)(nt * 16 + n) * BKS_ + q * 8);
            acc[nt] = __builtin_amdgcn_mfma_f32_16x16x32_bf16(af, bf, acc[nt], 0, 0, 0);
        }
        #pragma unroll
        for (int nt = 0; nt < 6; nt++) {
            const float bias = b_bh[nt * 16 + n];
            #pragma unroll
            for (int r = 0; r < 4; r++) {
                rbh_ws[(size_t)(row0 + q * 4 + r) * H_ + nt * 16 + n] =
                    f2bf(fmaxf(acc[nt][r] + bias, 0.0f));
            }
        }
    } else {
        // ---- W_out repack: chunk c = k8*128 + n2 ; src = W_out[n2][k8*8..+8] ----
        const int c = (blk - 56) * 256 + tid;   // 0..1535
        const int k8 = c >> 7;
        const int n2 = c & 127;
        const float* src = W_out + (size_t)n2 * H_ + k8 * 8;
        unsigned short tmp[8];
        #pragma unroll
        for (int j = 0; j < 8; j++) tmp[j] = f2bf(src[j]);
        i32x4 v;
        v.x = (int)((unsigned)tmp[0] | ((unsigned)tmp[1] << 16));
        v.y = (int)((unsigned)tmp[2] | ((unsigned)tmp[3] << 16));
        v.z = (int)((unsigned)tmp[4] | ((unsigned)tmp[5] << 16));
        v.w = (int)((unsigned)tmp[6] | ((unsigned)tmp[7] << 16));
        ((i32x4*)w_ws)[c] = v;
    }
}

// ---------------------------------------------------------------------------
// Main kernel: block = 256 thr (4 waves). Block tile: 28 t x 16 u x 128 v.
// W_out staged in LDS ONCE per block; rbh fragments hoisted to registers.
// Wave w, iteration i handles t = t0 + i*4 + w (7 iters/wave).
// ---------------------------------------------------------------------------
#define TT_ 7
__global__ __launch_bounds__(256) void joiner_kernel(
    const unsigned short* __restrict__ sh_ws,
    const unsigned short* __restrict__ rbh_ws,
    const unsigned short* __restrict__ w_ws,
    const float* __restrict__ b_out,
    float* __restrict__ out)
{
    __shared__ unsigned short Wl[12 * 128 * 8];   // 24 KB: [k8][n][8]

    const int tid = threadIdx.x;
    const int u0  = blockIdx.x * 16;
    const int t0  = blockIdx.y * (4 * TT_);
    const int bb  = blockIdx.z;

    // ---- stage W_out fragments (contiguous 16B chunks, conflict-free) ----
    {
        const i32x4* src = (const i32x4*)w_ws;
        i32x4* dst = (i32x4*)Wl;
        #pragma unroll
        for (int i = 0; i < 6; i++) {
            const int c = i * 256 + tid;
            dst[c] = src[c];
        }
    }
    __syncthreads();

    const int wave = tid >> 6;
    const int lane = tid & 63;
    const int n    = lane & 15;   // v-within-tile; also u for A frag
    const int q    = lane >> 4;   // k-quad

    // rbh fragments: t-invariant, straight from L2 (16B per lane)
    bf16x8 rb[3];
    #pragma unroll
    for (int ks = 0; ks < 3; ks++)
        rb[ks] = *(const bf16x8*)(rbh_ws +
            ((size_t)(bb * U_ + u0 + n)) * H_ + ks * 32 + q * 8);

    // bias: t-invariant
    float bias[8];
    #pragma unroll
    for (int nt = 0; nt < 8; nt++) bias[nt] = b_out[nt * 16 + n];

    for (int i = 0; i < TT_; i++) {
        const int t = t0 + i * 4 + wave;

        // sh fragments for this t (quad-broadcast 16B loads, L1/L2 hit)
        const unsigned short* shrow = sh_ws + ((size_t)(bb * T_ + t)) * H_;
        bf16x8 af[3];
        #pragma unroll
        for (int ks = 0; ks < 3; ks++) {
            const bf16x8 sf = *(const bf16x8*)(shrow + ks * 32 + q * 8);
            #pragma unroll
            for (int j = 0; j < 8; j++) {
                const float z = bf2f((unsigned short)sf[j]) *
                                bf2f((unsigned short)rb[ks][j]);
                af[ks][j] = (short)f2bf(z);
            }
        }

        f32x4 acc[8];
        #pragma unroll
        for (int nt = 0; nt < 8; nt++) acc[nt] = (f32x4){0.f, 0.f, 0.f, 0.f};

        #pragma unroll
        for (int ks = 0; ks < 3; ks++) {
            #pragma unroll
            for (int nt = 0; nt < 8; nt++) {
                const bf16x8 bfr = *(const bf16x8*)(Wl +
                    ((size_t)((ks * 4 + q) * 128 + nt * 16 + n)) * 8);
                acc[nt] = __builtin_amdgcn_mfma_f32_16x16x32_bf16(af[ks], bfr, acc[nt], 0, 0, 0);
            }
        }

        // ---- epilogue: bias + log_softmax over v (row = one 16-lane quad) ----
        #pragma unroll
        for (int nt = 0; nt < 8; nt++) {
            #pragma unroll
            for (int r = 0; r < 4; r++) acc[nt][r] += bias[nt];
        }

        #pragma unroll
        for (int r = 0; r < 4; r++) {
            float m = acc[0][r];
            #pragma unroll
            for (int nt = 1; nt < 8; nt++) m = fmaxf(m, acc[nt][r]);
            #pragma unroll
            for (int sft = 1; sft <= 8; sft <<= 1)
                m = fmaxf(m, __shfl_xor(m, sft, 64));

            float ssum = 0.0f;
            #pragma unroll
            for (int nt = 0; nt < 8; nt++) ssum += __expf(acc[nt][r] - m);
            #pragma unroll
            for (int sft = 1; sft <= 8; sft <<= 1)
                ssum += __shfl_xor(ssum, sft, 64);

            const float logz = m + __logf(ssum);
            const int u_local = q * 4 + r;
            float* orow = out + (((size_t)(bb * T_ + t)) * U_ + (u0 + u_local)) * V_;
            #pragma unroll
            for (int nt = 0; nt < 8; nt++)
                orow[nt * 16 + n] = acc[nt][r] - logz;
        }
    }
}

extern "C" void kernel_launch(void* const* d_in, const int* in_sizes, int n_in,
                              void* d_out, int out_size, void* d_ws, size_t ws_size,
                              hipStream_t stream)
{
    const float* s     = (const float*)d_in[0];
    const float* b     = (const float*)d_in[1];
    const float* W_sh  = (const float*)d_in[2];
    const float* b_sh  = (const float*)d_in[3];
    const float* W_bh  = (const float*)d_in[4];
    const float* b_bh  = (const float*)d_in[5];
    const float* W_out = (const float*)d_in[6];
    const float* b_out = (const float*)d_in[7];
    float* out = (float*)d_out;

    unsigned short* sh_ws  = (unsigned short*)d_ws;
    unsigned short* rbh_ws = sh_ws + (size_t)B_ * T_ * H_;    // +344064 B
    unsigned short* w_ws   = rbh_ws + (size_t)B_ * U_ * H_;   // +344064 B (16B aligned)

    prep_kernel<<<62, 256, 0, stream>>>(
        s, b, W_sh, b_sh, W_bh, b_bh, W_out, sh_ws, rbh_ws, w_ws);

    joiner_kernel<<<dim3(U_ / 16, T_ / (4 * TT_), B_), 256, 0, stream>>>(
        sh_ws, rbh_ws, w_ws, b_out, out);
}